// Round 5
// baseline (195.178 us; speedup 1.0000x reference)
//
#include <hip/hip_runtime.h>

#define NB 8
#define NN 2048
#define NM 8192
#define NC 64
#define ND 64
#define NK 16

#define PARTS 8     // lanes per query
#define PPT 256     // points per lane (NN / PARTS)
#define CHUNK 260   // padded chunk stride in floats: 260%32==4 -> parts on
                    // distinct bank-quads -> conflict-free ds_read_b128
#define QPB 32      // query-slots per round (256 threads / 8 parts)
#define QROUNDS 2   // sequential rounds per block -> 64 queries per block
#define NG 8        // groups of 32 points per lane
#define CAP 64      // candidate slots per query (overflow prob ~e^-40 + exact fallback)

// ---------------------------------------------------------------------------
// Kernel 1: feats = transpose(features), x = feats @ W1^T + b1  (unchanged)
// ---------------------------------------------------------------------------
__global__ __launch_bounds__(256) void feats_linear_kernel(
    const float* __restrict__ features, const float* __restrict__ W1,
    const float* __restrict__ b1, float* __restrict__ out_feats,
    float* __restrict__ out_x) {
  __shared__ float tile[NC][68];
  __shared__ float Wt[NC][68];

  const int b = blockIdx.y;
  const int n0 = blockIdx.x * 64;
  const int t = threadIdx.x;
  const int lane = t & 63;
  const int grp = t >> 6;

  for (int c = grp; c < NC; c += 4)
    tile[c][lane] = features[((size_t)(b * NC + c) * NN) + n0 + lane];
  for (int i = t; i < NC * ND; i += 256) {
    const int d = i >> 6, c = i & 63;
    Wt[c][d] = W1[i];
  }
  __syncthreads();

  for (int j = grp; j < 64; j += 4)
    out_feats[((size_t)(b * NN + n0 + j) * NC) + lane] = tile[lane][j];

  const int d = lane;
  float acc[16];
  const float bd = b1[d];
#pragma unroll
  for (int jj = 0; jj < 16; jj++) acc[jj] = bd;

  const float4* tv = (const float4*)&tile[0][0];
  for (int c = 0; c < NC; c++) {
    const float w = Wt[c][d];
#pragma unroll
    for (int q = 0; q < 4; q++) {
      const float4 v = tv[c * 17 + grp * 4 + q];
      acc[q * 4 + 0] = fmaf(v.x, w, acc[q * 4 + 0]);
      acc[q * 4 + 1] = fmaf(v.y, w, acc[q * 4 + 1]);
      acc[q * 4 + 2] = fmaf(v.z, w, acc[q * 4 + 2]);
      acc[q * 4 + 3] = fmaf(v.w, w, acc[q * 4 + 3]);
    }
  }
#pragma unroll
  for (int jj = 0; jj < 16; jj++) {
    const int j = grp * 16 + jj;
    out_x[((size_t)(b * NN + n0 + j) * ND) + d] = acc[jj];
  }
}

// ---------------------------------------------------------------------------
// Kernel 2: exact stable kNN via group-min threshold bound.
// Delta vs validated r2: the ENTIRE post-staging pipeline (verbatim r2 text)
// runs QROUNDS=2 times sequentially per block, amortizing point staging and
// halving the grid. No concurrently-live multi-query state.
// ---------------------------------------------------------------------------
__device__ __forceinline__ float d2rn(float qx, float qy, float qz, float x,
                                      float y, float z) {
  const float dx = __fsub_rn(qx, x);
  const float dy = __fsub_rn(qy, y);
  const float dz = __fsub_rn(qz, z);
  return __fadd_rn(__fadd_rn(__fmul_rn(dx, dx), __fmul_rn(dy, dy)),
                   __fmul_rn(dz, dz));
}

#define CE(a, i, j)                     \
  {                                     \
    const float lo = fminf(a[i], a[j]); \
    const float hi = fmaxf(a[i], a[j]); \
    a[i] = lo;                          \
    a[j] = hi;                          \
  }

// Batcher odd-even sort of d[8] ascending (19 comparators)
#define SORT8(d)                                  \
  CE(d, 0, 1) CE(d, 2, 3) CE(d, 4, 5) CE(d, 6, 7) \
  CE(d, 0, 2) CE(d, 1, 3) CE(d, 4, 6) CE(d, 5, 7) \
  CE(d, 1, 2) CE(d, 5, 6)                         \
  CE(d, 0, 4) CE(d, 1, 5) CE(d, 2, 6) CE(d, 3, 7) \
  CE(d, 2, 4) CE(d, 3, 5)                         \
  CE(d, 1, 2) CE(d, 3, 4) CE(d, 5, 6)

// bitonic sort of L[16] (input bitonic) ascending: 32 comparators
#define BITONIC16(L)                                                      \
  CE(L, 0, 8) CE(L, 1, 9) CE(L, 2, 10) CE(L, 3, 11) CE(L, 4, 12)          \
  CE(L, 5, 13) CE(L, 6, 14) CE(L, 7, 15)                                  \
  CE(L, 0, 4) CE(L, 1, 5) CE(L, 2, 6) CE(L, 3, 7) CE(L, 8, 12)            \
  CE(L, 9, 13) CE(L, 10, 14) CE(L, 11, 15)                                \
  CE(L, 0, 2) CE(L, 1, 3) CE(L, 4, 6) CE(L, 5, 7) CE(L, 8, 10)            \
  CE(L, 9, 11) CE(L, 12, 14) CE(L, 13, 15)                                \
  CE(L, 0, 1) CE(L, 2, 3) CE(L, 4, 5) CE(L, 6, 7) CE(L, 8, 9)             \
  CE(L, 10, 11) CE(L, 12, 13) CE(L, 14, 15)

__device__ __forceinline__ void dist8(const float* px, const float* py,
                                      const float* pz, int base, float qx,
                                      float qy, float qz, float d[8]) {
  const float4 X0 = *(const float4*)&px[base];
  const float4 X1 = *(const float4*)&px[base + 4];
  const float4 Y0 = *(const float4*)&py[base];
  const float4 Y1 = *(const float4*)&py[base + 4];
  const float4 Z0 = *(const float4*)&pz[base];
  const float4 Z1 = *(const float4*)&pz[base + 4];
  d[0] = d2rn(qx, qy, qz, X0.x, Y0.x, Z0.x);
  d[1] = d2rn(qx, qy, qz, X0.y, Y0.y, Z0.y);
  d[2] = d2rn(qx, qy, qz, X0.z, Y0.z, Z0.z);
  d[3] = d2rn(qx, qy, qz, X0.w, Y0.w, Z0.w);
  d[4] = d2rn(qx, qy, qz, X1.x, Y1.x, Z1.x);
  d[5] = d2rn(qx, qy, qz, X1.y, Y1.y, Z1.y);
  d[6] = d2rn(qx, qy, qz, X1.z, Y1.z, Z1.z);
  d[7] = d2rn(qx, qy, qz, X1.w, Y1.w, Z1.w);
}

__device__ __forceinline__ float min8(const float d[8]) {
  return fminf(fminf(fminf(d[0], d[1]), fminf(d[2], d[3])),
               fminf(fminf(d[4], d[5]), fminf(d[6], d[7])));
}

__global__ __launch_bounds__(256, 4) void knn_kernel(
    const float* __restrict__ xyz, const float* __restrict__ xyz_fp,
    float* __restrict__ out_knn) {
  __shared__ __align__(16) float px[PARTS * CHUNK];
  __shared__ __align__(16) float py[PARTS * CHUNK];
  __shared__ __align__(16) float pz[PARTS * CHUNK];
  __shared__ unsigned short cand[QPB * CAP];
  __shared__ int ccnt[QPB];

  const int b = blockIdx.y;
  const int t = threadIdx.x;
  const int ql = t >> 3;   // query-local 0..31
  const int part = t & 7;  // 0..7

  // stage points SoA, chunked per part with +4 float pad (verbatim r2)
  const float* P = xyz + (size_t)b * NN * 3;
  for (int i = t; i < NN; i += 256) {
    const int slot = (i >> 8) * CHUNK + (i & 255);
    px[slot] = P[3 * i + 0];
    py[slot] = P[3 * i + 1];
    pz[slot] = P[3 * i + 2];
  }

  const int pbase = part * CHUNK;

#pragma unroll 1
  for (int h = 0; h < QROUNDS; h++) {
    // re-zero counters; barrier also orders staging (h=0) and the previous
    // round's cand-reads (h=1) against this round's pass-2 writes
    if (t < QPB) ccnt[t] = 0;
    __syncthreads();

    const int q = blockIdx.x * (QPB * QROUNDS) + h * QPB + ql;
    const float* Q = xyz_fp + ((size_t)b * NM + q) * 3;
    const float qx = Q[0], qy = Q[1], qz = Q[2];

    // ---- pass 1: group mins (8 groups of 32 points per lane) ----
    float gmin[NG];
#pragma unroll
    for (int g = 0; g < NG; g++) {
      float gm = 3.0e38f;
#pragma unroll
      for (int bb = 0; bb < 4; bb++) {
        float d[8];
        dist8(px, py, pz, pbase + g * 32 + bb * 8, qx, qy, qz, d);
        gm = fminf(gm, min8(d));
      }
      gmin[g] = gm;
    }

    // ---- T = 16th-smallest of the query's 64 group-mins ----
    float s[16];
    {
      float g8[NG];
#pragma unroll
      for (int g = 0; g < NG; g++) g8[g] = gmin[g];
      SORT8(g8)
#pragma unroll
      for (int j = 0; j < 8; j++) s[j] = g8[j];
#pragma unroll
      for (int j = 8; j < 16; j++) s[j] = 3.0e38f;
    }
#pragma unroll
    for (int mask = 1; mask <= 4; mask <<= 1) {
      float B[16];
#pragma unroll
      for (int j = 0; j < 16; j++) B[j] = __shfl_xor(s[j], mask, 64);
      float L[16];
#pragma unroll
      for (int j = 0; j < 16; j++) L[j] = fminf(s[j], B[15 - j]);
      BITONIC16(L)
#pragma unroll
      for (int j = 0; j < 16; j++) s[j] = L[j];
    }
    const float T = s[15];

    // ---- per-lane 8-bit pass mask ----
    unsigned m8 = 0;
#pragma unroll
    for (int g = 0; g < NG; g++) m8 |= (gmin[g] <= T) ? (1u << g) : 0u;

    // ---- butterfly-OR across the query's 8 lanes -> 64-bit group mask ----
    unsigned lo = (part < 4) ? (m8 << (8 * part)) : 0u;
    unsigned hi = (part >= 4) ? (m8 << (8 * (part - 4))) : 0u;
#pragma unroll
    for (int mk = 1; mk <= 4; mk <<= 1) {
      lo |= __shfl_xor(lo, mk, 64);
      hi |= __shfl_xor(hi, mk, 64);
    }
    const unsigned long long vm = ((unsigned long long)hi << 32) | lo;

    // ---- round-robin: k-th set bit -> lane (k & 7) ----
    unsigned long long mym = 0ull;
    {
      unsigned long long m = vm;
      int cnt = 0;
      while (m) {
        const unsigned long long lb = m & (0ull - m);
        if ((cnt & 7) == part) mym |= lb;
        m ^= lb;
        cnt++;
      }
    }

    // ---- pass 2: scan assigned groups, collect candidates ----
    while (mym) {
      const int gid = __ffsll(mym) - 1;
      mym &= mym - 1;
      const int gb = (gid >> 3) * CHUNK + (gid & 7) * 32;
      const int ib = (gid >> 3) * PPT + (gid & 7) * 32;
#pragma unroll
      for (int bb = 0; bb < 4; bb++) {
        float d[8];
        dist8(px, py, pz, gb + bb * 8, qx, qy, qz, d);
        if (min8(d) <= T) {
#pragma unroll
          for (int j = 0; j < 8; j++) {
            if (d[j] <= T) {
              const int pos = atomicAdd(&ccnt[ql], 1);
              if (pos < CAP)
                cand[ql * CAP + pos] = (unsigned short)(ib + bb * 8 + j);
            }
          }
        }
      }
    }
    __syncthreads();

    // ---- phase 3: exact stable top-16 by (d2, idx) u64 keys ----
    if (part == 0) {
      const int cnt = ccnt[ql];
      unsigned long long kb[NK];
#pragma unroll
      for (int j = 0; j < NK; j++) kb[j] = ~0ULL;

      if (cnt <= CAP) {
        for (int c = 0; c < cnt; c++) {
          const int i = cand[ql * CAP + c];
          const int slot = (i >> 8) * CHUNK + (i & 255);
          const float d2 = d2rn(qx, qy, qz, px[slot], py[slot], pz[slot]);
          unsigned long long kk =
              ((unsigned long long)__float_as_uint(d2) << 32) | (unsigned)i;
          if (kk < kb[NK - 1]) {
#pragma unroll
            for (int j = 0; j < NK; j++) {
              const bool c2 = kk < kb[j];
              const unsigned long long lo2 = c2 ? kk : kb[j];
              const unsigned long long hi2 = c2 ? kb[j] : kk;
              kb[j] = lo2;
              kk = hi2;
            }
          }
        }
      } else {
        // overflow fallback (astronomically rare): exact scan of all points
        for (int i = 0; i < NN; i++) {
          const int slot = (i >> 8) * CHUNK + (i & 255);
          const float d2 = d2rn(qx, qy, qz, px[slot], py[slot], pz[slot]);
          unsigned long long kk =
              ((unsigned long long)__float_as_uint(d2) << 32) | (unsigned)i;
          if (kk < kb[NK - 1]) {
#pragma unroll
            for (int j = 0; j < NK; j++) {
              const bool c2 = kk < kb[j];
              const unsigned long long lo2 = c2 ? kk : kb[j];
              const unsigned long long hi2 = c2 ? kb[j] : kk;
              kb[j] = lo2;
              kk = hi2;
            }
          }
        }
      }
#pragma unroll
      for (int j = 0; j < NK; j++)
        cand[ql * CAP + j] = (unsigned short)(unsigned)kb[j];
    }
    __syncthreads();

    // ---- output: each part lane writes 2 neighbors (6 floats) ----
    float* o = out_knn + ((size_t)(b * NM + q)) * (NK * 3);
#pragma unroll
    for (int jj = 0; jj < 2; jj++) {
      const int j = part * 2 + jj;
      const int i = cand[ql * CAP + j];
      const int slot = (i >> 8) * CHUNK + (i & 255);
      o[3 * j + 0] = px[slot];
      o[3 * j + 1] = py[slot];
      o[3 * j + 2] = pz[slot];
    }
  }
}

// ---------------------------------------------------------------------------
extern "C" void kernel_launch(void* const* d_in, const int* in_sizes, int n_in,
                              void* d_out, int out_size, void* d_ws,
                              size_t ws_size, hipStream_t stream) {
  const float* xyz      = (const float*)d_in[0];  // [8,2048,3]
  const float* xyz_fp   = (const float*)d_in[1];  // [8,8192,3]
  const float* features = (const float*)d_in[2];  // [8,64,2048]
  const float* W1 = (const float*)d_in[4];        // [64,64]
  const float* b1 = (const float*)d_in[5];        // [64]

  float* out_feats = (float*)d_out;                       // 8*2048*64
  float* out_knn   = out_feats + (size_t)NB * NN * NC;    // 8*8192*16*3
  float* out_x     = out_knn + (size_t)NB * NM * NK * 3;  // 8*2048*64

  feats_linear_kernel<<<dim3(NN / 64, NB), 256, 0, stream>>>(
      features, W1, b1, out_feats, out_x);
  knn_kernel<<<dim3(NM / (QPB * QROUNDS), NB), 256, 0, stream>>>(xyz, xyz_fp,
                                                                 out_knn);
}

// Round 6
// 188.977 us; speedup vs baseline: 1.0328x; 1.0328x over previous
//
#include <hip/hip_runtime.h>

#define NB 8
#define NN 2048
#define NM 8192
#define NC 64
#define ND 64
#define NK 16

#define PARTS 8     // lanes per query
#define PPT 256     // points per lane (NN / PARTS)
#define CHUNK 260   // padded chunk stride in floats: 260%32==4 -> parts on
                    // distinct bank-quads -> conflict-free ds_read_b128
#define QPB 32      // queries per block (256 threads / 8 parts)
#define NG 8        // groups of 32 points per lane
#define CAP 64      // candidate slots per query (overflow prob ~e^-40 + exact fallback)

#define FB (NN / 64)        // feats blocks per batch (32)
#define KB (NM / QPB)       // knn blocks per batch (256)
#define SMEM_BYTES 34816    // max(feats 2*64*68*4 = 34816, knn 29184)

__device__ __forceinline__ float d2rn(float qx, float qy, float qz, float x,
                                      float y, float z) {
  const float dx = __fsub_rn(qx, x);
  const float dy = __fsub_rn(qy, y);
  const float dz = __fsub_rn(qz, z);
  return __fadd_rn(__fadd_rn(__fmul_rn(dx, dx), __fmul_rn(dy, dy)),
                   __fmul_rn(dz, dz));
}

#define CE(a, i, j)                     \
  {                                     \
    const float lo = fminf(a[i], a[j]); \
    const float hi = fmaxf(a[i], a[j]); \
    a[i] = lo;                          \
    a[j] = hi;                          \
  }

// Batcher odd-even sort of d[8] ascending (19 comparators)
#define SORT8(d)                                  \
  CE(d, 0, 1) CE(d, 2, 3) CE(d, 4, 5) CE(d, 6, 7) \
  CE(d, 0, 2) CE(d, 1, 3) CE(d, 4, 6) CE(d, 5, 7) \
  CE(d, 1, 2) CE(d, 5, 6)                         \
  CE(d, 0, 4) CE(d, 1, 5) CE(d, 2, 6) CE(d, 3, 7) \
  CE(d, 2, 4) CE(d, 3, 5)                         \
  CE(d, 1, 2) CE(d, 3, 4) CE(d, 5, 6)

// bitonic sort of L[16] (input bitonic) ascending: 32 comparators
#define BITONIC16(L)                                                      \
  CE(L, 0, 8) CE(L, 1, 9) CE(L, 2, 10) CE(L, 3, 11) CE(L, 4, 12)          \
  CE(L, 5, 13) CE(L, 6, 14) CE(L, 7, 15)                                  \
  CE(L, 0, 4) CE(L, 1, 5) CE(L, 2, 6) CE(L, 3, 7) CE(L, 8, 12)            \
  CE(L, 9, 13) CE(L, 10, 14) CE(L, 11, 15)                                \
  CE(L, 0, 2) CE(L, 1, 3) CE(L, 4, 6) CE(L, 5, 7) CE(L, 8, 10)            \
  CE(L, 9, 11) CE(L, 12, 14) CE(L, 13, 15)                                \
  CE(L, 0, 1) CE(L, 2, 3) CE(L, 4, 5) CE(L, 6, 7) CE(L, 8, 9)             \
  CE(L, 10, 11) CE(L, 12, 13) CE(L, 14, 15)

__device__ __forceinline__ void dist8(const float* px, const float* py,
                                      const float* pz, int base, float qx,
                                      float qy, float qz, float d[8]) {
  const float4 X0 = *(const float4*)&px[base];
  const float4 X1 = *(const float4*)&px[base + 4];
  const float4 Y0 = *(const float4*)&py[base];
  const float4 Y1 = *(const float4*)&py[base + 4];
  const float4 Z0 = *(const float4*)&pz[base];
  const float4 Z1 = *(const float4*)&pz[base + 4];
  d[0] = d2rn(qx, qy, qz, X0.x, Y0.x, Z0.x);
  d[1] = d2rn(qx, qy, qz, X0.y, Y0.y, Z0.y);
  d[2] = d2rn(qx, qy, qz, X0.z, Y0.z, Z0.z);
  d[3] = d2rn(qx, qy, qz, X0.w, Y0.w, Z0.w);
  d[4] = d2rn(qx, qy, qz, X1.x, Y1.x, Z1.x);
  d[5] = d2rn(qx, qy, qz, X1.y, Y1.y, Z1.y);
  d[6] = d2rn(qx, qy, qz, X1.z, Y1.z, Z1.z);
  d[7] = d2rn(qx, qy, qz, X1.w, Y1.w, Z1.w);
}

__device__ __forceinline__ float min8(const float d[8]) {
  return fminf(fminf(fminf(d[0], d[1]), fminf(d[2], d[3])),
               fminf(fminf(d[4], d[5]), fminf(d[6], d[7])));
}

// ---------------------------------------------------------------------------
// Fused kernel: blockIdx.x < FB -> feats/linear path (verbatim r2 kernel 1);
//               else            -> kNN path (verbatim r2 kernel 2).
// One launch; LDS union; barriers are block-uniform (branch on blockIdx).
// ---------------------------------------------------------------------------
__global__ __launch_bounds__(256, 4) void fused_kernel(
    const float* __restrict__ features, const float* __restrict__ W1,
    const float* __restrict__ b1, float* __restrict__ out_feats,
    float* __restrict__ out_x, const float* __restrict__ xyz,
    const float* __restrict__ xyz_fp, float* __restrict__ out_knn) {
  __shared__ __align__(16) unsigned char smem[SMEM_BYTES];

  const int b = blockIdx.y;
  const int t = threadIdx.x;

  if (blockIdx.x < FB) {
    // ================= feats + linear path (verbatim r2) =================
    float(*tile)[68] = reinterpret_cast<float(*)[68]>(smem);
    float(*Wt)[68] = reinterpret_cast<float(*)[68]>(smem + NC * 68 * 4);

    const int n0 = blockIdx.x * 64;
    const int lane = t & 63;
    const int grp = t >> 6;

    for (int c = grp; c < NC; c += 4)
      tile[c][lane] = features[((size_t)(b * NC + c) * NN) + n0 + lane];
    for (int i = t; i < NC * ND; i += 256) {
      const int d = i >> 6, c = i & 63;
      Wt[c][d] = W1[i];
    }
    __syncthreads();

    for (int j = grp; j < 64; j += 4)
      out_feats[((size_t)(b * NN + n0 + j) * NC) + lane] = tile[lane][j];

    const int d = lane;
    float acc[16];
    const float bd = b1[d];
#pragma unroll
    for (int jj = 0; jj < 16; jj++) acc[jj] = bd;

    const float4* tv = (const float4*)&tile[0][0];
    for (int c = 0; c < NC; c++) {
      const float w = Wt[c][d];
#pragma unroll
      for (int q = 0; q < 4; q++) {
        const float4 v = tv[c * 17 + grp * 4 + q];
        acc[q * 4 + 0] = fmaf(v.x, w, acc[q * 4 + 0]);
        acc[q * 4 + 1] = fmaf(v.y, w, acc[q * 4 + 1]);
        acc[q * 4 + 2] = fmaf(v.z, w, acc[q * 4 + 2]);
        acc[q * 4 + 3] = fmaf(v.w, w, acc[q * 4 + 3]);
      }
    }
#pragma unroll
    for (int jj = 0; jj < 16; jj++) {
      const int j = grp * 16 + jj;
      out_x[((size_t)(b * NN + n0 + j) * ND) + d] = acc[jj];
    }
    return;
  }

  // ======================= kNN path (verbatim r2) =======================
  float* px = reinterpret_cast<float*>(smem);
  float* py = px + PARTS * CHUNK;
  float* pz = py + PARTS * CHUNK;
  unsigned short* cand =
      reinterpret_cast<unsigned short*>(smem + 3 * PARTS * CHUNK * 4);
  int* ccnt =
      reinterpret_cast<int*>(smem + 3 * PARTS * CHUNK * 4 + QPB * CAP * 2);

  const int ql = t >> 3;   // query-local 0..31
  const int part = t & 7;  // 0..7

  if (t < QPB) ccnt[t] = 0;

  // stage points SoA, chunked per part with +4 float pad
  const float* P = xyz + (size_t)b * NN * 3;
  for (int i = t; i < NN; i += 256) {
    const int slot = (i >> 8) * CHUNK + (i & 255);
    px[slot] = P[3 * i + 0];
    py[slot] = P[3 * i + 1];
    pz[slot] = P[3 * i + 2];
  }
  __syncthreads();

  const int q = (blockIdx.x - FB) * QPB + ql;
  const float* Q = xyz_fp + ((size_t)b * NM + q) * 3;
  const float qx = Q[0], qy = Q[1], qz = Q[2];

  const int pbase = part * CHUNK;

  // ---- pass 1: group mins (8 groups of 32 points per lane) ----
  float gmin[NG];
#pragma unroll
  for (int g = 0; g < NG; g++) {
    float gm = 3.0e38f;
#pragma unroll
    for (int bb = 0; bb < 4; bb++) {
      float d[8];
      dist8(px, py, pz, pbase + g * 32 + bb * 8, qx, qy, qz, d);
      gm = fminf(gm, min8(d));
    }
    gmin[g] = gm;
  }

  // ---- T = 16th-smallest of the query's 64 group-mins ----
  float s[16];
  {
    float g8[NG];
#pragma unroll
    for (int g = 0; g < NG; g++) g8[g] = gmin[g];
    SORT8(g8)
#pragma unroll
    for (int j = 0; j < 8; j++) s[j] = g8[j];
#pragma unroll
    for (int j = 8; j < 16; j++) s[j] = 3.0e38f;
  }
#pragma unroll
  for (int mask = 1; mask <= 4; mask <<= 1) {
    float B[16];
#pragma unroll
    for (int j = 0; j < 16; j++) B[j] = __shfl_xor(s[j], mask, 64);
    float L[16];
#pragma unroll
    for (int j = 0; j < 16; j++) L[j] = fminf(s[j], B[15 - j]);
    BITONIC16(L)
#pragma unroll
    for (int j = 0; j < 16; j++) s[j] = L[j];
  }
  const float T = s[15];

  // ---- per-lane 8-bit pass mask ----
  unsigned m8 = 0;
#pragma unroll
  for (int g = 0; g < NG; g++) m8 |= (gmin[g] <= T) ? (1u << g) : 0u;

  // ---- butterfly-OR across the query's 8 lanes -> 64-bit group mask ----
  unsigned lo = (part < 4) ? (m8 << (8 * part)) : 0u;
  unsigned hi = (part >= 4) ? (m8 << (8 * (part - 4))) : 0u;
#pragma unroll
  for (int mk = 1; mk <= 4; mk <<= 1) {
    lo |= __shfl_xor(lo, mk, 64);
    hi |= __shfl_xor(hi, mk, 64);
  }
  const unsigned long long vm = ((unsigned long long)hi << 32) | lo;

  // ---- round-robin: k-th set bit -> lane (k & 7) ----
  unsigned long long mym = 0ull;
  {
    unsigned long long m = vm;
    int cnt = 0;
    while (m) {
      const unsigned long long lb = m & (0ull - m);
      if ((cnt & 7) == part) mym |= lb;
      m ^= lb;
      cnt++;
    }
  }

  // ---- pass 2: scan assigned groups (any chunk), collect candidates ----
  while (mym) {
    const int gid = __ffsll(mym) - 1;
    mym &= mym - 1;
    const int gb = (gid >> 3) * CHUNK + (gid & 7) * 32;
    const int ib = (gid >> 3) * PPT + (gid & 7) * 32;
#pragma unroll
    for (int bb = 0; bb < 4; bb++) {
      float d[8];
      dist8(px, py, pz, gb + bb * 8, qx, qy, qz, d);
      if (min8(d) <= T) {
#pragma unroll
        for (int j = 0; j < 8; j++) {
          if (d[j] <= T) {
            const int pos = atomicAdd(&ccnt[ql], 1);
            if (pos < CAP)
              cand[ql * CAP + pos] = (unsigned short)(ib + bb * 8 + j);
          }
        }
      }
    }
  }
  __syncthreads();

  // ---- phase 3: exact stable top-16 by (d2, idx) u64 keys ----
  if (part == 0) {
    const int cnt = ccnt[ql];
    unsigned long long kb[NK];
#pragma unroll
    for (int j = 0; j < NK; j++) kb[j] = ~0ULL;

    if (cnt <= CAP) {
      for (int c = 0; c < cnt; c++) {
        const int i = cand[ql * CAP + c];
        const int slot = (i >> 8) * CHUNK + (i & 255);
        const float d2 = d2rn(qx, qy, qz, px[slot], py[slot], pz[slot]);
        unsigned long long kk =
            ((unsigned long long)__float_as_uint(d2) << 32) | (unsigned)i;
        if (kk < kb[NK - 1]) {
#pragma unroll
          for (int j = 0; j < NK; j++) {
            const bool c2 = kk < kb[j];
            const unsigned long long lo2 = c2 ? kk : kb[j];
            const unsigned long long hi2 = c2 ? kb[j] : kk;
            kb[j] = lo2;
            kk = hi2;
          }
        }
      }
    } else {
      // overflow fallback (astronomically rare): exact scan of all points
      for (int i = 0; i < NN; i++) {
        const int slot = (i >> 8) * CHUNK + (i & 255);
        const float d2 = d2rn(qx, qy, qz, px[slot], py[slot], pz[slot]);
        unsigned long long kk =
            ((unsigned long long)__float_as_uint(d2) << 32) | (unsigned)i;
        if (kk < kb[NK - 1]) {
#pragma unroll
          for (int j = 0; j < NK; j++) {
            const bool c2 = kk < kb[j];
            const unsigned long long lo2 = c2 ? kk : kb[j];
            const unsigned long long hi2 = c2 ? kb[j] : kk;
            kb[j] = lo2;
            kk = hi2;
          }
        }
      }
    }
#pragma unroll
    for (int j = 0; j < NK; j++)
      cand[ql * CAP + j] = (unsigned short)(unsigned)kb[j];
  }
  __syncthreads();

  // ---- output: each part lane writes 2 neighbors (6 floats) ----
  float* o = out_knn + ((size_t)(b * NM + q)) * (NK * 3);
#pragma unroll
  for (int jj = 0; jj < 2; jj++) {
    const int j = part * 2 + jj;
    const int i = cand[ql * CAP + j];
    const int slot = (i >> 8) * CHUNK + (i & 255);
    o[3 * j + 0] = px[slot];
    o[3 * j + 1] = py[slot];
    o[3 * j + 2] = pz[slot];
  }
}

// ---------------------------------------------------------------------------
extern "C" void kernel_launch(void* const* d_in, const int* in_sizes, int n_in,
                              void* d_out, int out_size, void* d_ws,
                              size_t ws_size, hipStream_t stream) {
  const float* xyz      = (const float*)d_in[0];  // [8,2048,3]
  const float* xyz_fp   = (const float*)d_in[1];  // [8,8192,3]
  const float* features = (const float*)d_in[2];  // [8,64,2048]
  const float* W1 = (const float*)d_in[4];        // [64,64]
  const float* b1 = (const float*)d_in[5];        // [64]

  float* out_feats = (float*)d_out;                       // 8*2048*64
  float* out_knn   = out_feats + (size_t)NB * NN * NC;    // 8*8192*16*3
  float* out_x     = out_knn + (size_t)NB * NM * NK * 3;  // 8*2048*64

  fused_kernel<<<dim3(FB + KB, NB), 256, 0, stream>>>(
      features, W1, b1, out_feats, out_x, xyz, xyz_fp, out_knn);
}

// Round 7
// 186.792 us; speedup vs baseline: 1.0449x; 1.0117x over previous
//
#include <hip/hip_runtime.h>

#define NB 8
#define NN 2048
#define NM 8192
#define NC 64
#define ND 64
#define NK 16

#define PARTS 8     // lanes per query
#define PPT 256     // points per lane (NN / PARTS)
#define CHUNK 260   // padded chunk stride in floats: 260%32==4 -> parts on
                    // distinct bank-quads -> conflict-free ds_read_b128
#define QPB 32      // queries per block (256 threads / 8 parts)
#define NG 8        // groups of 32 points per lane
#define CAP 64      // candidate slots per query (overflow prob ~e^-40 + exact fallback)

#define KB (NM / QPB)       // knn blocks per batch (256) -- FIRST in grid
#define FB (NN / 64)        // feats blocks per batch (32) -- after knn
#define SMEM_BYTES 29184    // knn: 3*8*260*4 + 32*64*2 + 32*4 = 29184
                            // feats: tile only = 64*68*4 = 17408 (W in regs)

__device__ __forceinline__ float d2rn(float qx, float qy, float qz, float x,
                                      float y, float z) {
  const float dx = __fsub_rn(qx, x);
  const float dy = __fsub_rn(qy, y);
  const float dz = __fsub_rn(qz, z);
  return __fadd_rn(__fadd_rn(__fmul_rn(dx, dx), __fmul_rn(dy, dy)),
                   __fmul_rn(dz, dz));
}

#define CE(a, i, j)                     \
  {                                     \
    const float lo = fminf(a[i], a[j]); \
    const float hi = fmaxf(a[i], a[j]); \
    a[i] = lo;                          \
    a[j] = hi;                          \
  }

// Batcher odd-even sort of d[8] ascending (19 comparators)
#define SORT8(d)                                  \
  CE(d, 0, 1) CE(d, 2, 3) CE(d, 4, 5) CE(d, 6, 7) \
  CE(d, 0, 2) CE(d, 1, 3) CE(d, 4, 6) CE(d, 5, 7) \
  CE(d, 1, 2) CE(d, 5, 6)                         \
  CE(d, 0, 4) CE(d, 1, 5) CE(d, 2, 6) CE(d, 3, 7) \
  CE(d, 2, 4) CE(d, 3, 5)                         \
  CE(d, 1, 2) CE(d, 3, 4) CE(d, 5, 6)

// bitonic sort of L[16] (input bitonic) ascending: 32 comparators
#define BITONIC16(L)                                                      \
  CE(L, 0, 8) CE(L, 1, 9) CE(L, 2, 10) CE(L, 3, 11) CE(L, 4, 12)          \
  CE(L, 5, 13) CE(L, 6, 14) CE(L, 7, 15)                                  \
  CE(L, 0, 4) CE(L, 1, 5) CE(L, 2, 6) CE(L, 3, 7) CE(L, 8, 12)            \
  CE(L, 9, 13) CE(L, 10, 14) CE(L, 11, 15)                                \
  CE(L, 0, 2) CE(L, 1, 3) CE(L, 4, 6) CE(L, 5, 7) CE(L, 8, 10)            \
  CE(L, 9, 11) CE(L, 12, 14) CE(L, 13, 15)                                \
  CE(L, 0, 1) CE(L, 2, 3) CE(L, 4, 5) CE(L, 6, 7) CE(L, 8, 9)             \
  CE(L, 10, 11) CE(L, 12, 13) CE(L, 14, 15)

__device__ __forceinline__ void dist8(const float* px, const float* py,
                                      const float* pz, int base, float qx,
                                      float qy, float qz, float d[8]) {
  const float4 X0 = *(const float4*)&px[base];
  const float4 X1 = *(const float4*)&px[base + 4];
  const float4 Y0 = *(const float4*)&py[base];
  const float4 Y1 = *(const float4*)&py[base + 4];
  const float4 Z0 = *(const float4*)&pz[base];
  const float4 Z1 = *(const float4*)&pz[base + 4];
  d[0] = d2rn(qx, qy, qz, X0.x, Y0.x, Z0.x);
  d[1] = d2rn(qx, qy, qz, X0.y, Y0.y, Z0.y);
  d[2] = d2rn(qx, qy, qz, X0.z, Y0.z, Z0.z);
  d[3] = d2rn(qx, qy, qz, X0.w, Y0.w, Z0.w);
  d[4] = d2rn(qx, qy, qz, X1.x, Y1.x, Z1.x);
  d[5] = d2rn(qx, qy, qz, X1.y, Y1.y, Z1.y);
  d[6] = d2rn(qx, qy, qz, X1.z, Y1.z, Z1.z);
  d[7] = d2rn(qx, qy, qz, X1.w, Y1.w, Z1.w);
}

__device__ __forceinline__ float min8(const float d[8]) {
  return fminf(fminf(fminf(d[0], d[1]), fminf(d[2], d[3])),
               fminf(fminf(d[4], d[5]), fminf(d[6], d[7])));
}

// ---------------------------------------------------------------------------
// Fused kernel: blockIdx.x < KB  -> kNN path (verbatim r2 kernel 2);
//               else             -> feats/linear path (W1 row in registers).
// One launch; LDS union capped at 29184 B -> 5 blocks/CU like r2.
// ---------------------------------------------------------------------------
__global__ __launch_bounds__(256, 4) void fused_kernel(
    const float* __restrict__ features, const float* __restrict__ W1,
    const float* __restrict__ b1, float* __restrict__ out_feats,
    float* __restrict__ out_x, const float* __restrict__ xyz,
    const float* __restrict__ xyz_fp, float* __restrict__ out_knn) {
  __shared__ __align__(16) unsigned char smem[SMEM_BYTES];

  const int b = blockIdx.y;
  const int t = threadIdx.x;

  if (blockIdx.x >= KB) {
    // ================= feats + linear path =================
    float(*tile)[68] = reinterpret_cast<float(*)[68]>(smem);  // 17408 B

    const int n0 = (blockIdx.x - KB) * 64;
    const int lane = t & 63;
    const int grp = t >> 6;

    for (int c = grp; c < NC; c += 4)
      tile[c][lane] = features[((size_t)(b * NC + c) * NN) + n0 + lane];

    // preload this thread's W1 row (w for d=lane, all c) into registers:
    // Wt[c][d] == W1[d*64 + c] -> row `lane` of W1, 16 float4 = 64 VGPR
    float4 wreg[16];
    {
      const float4* Wr = (const float4*)(W1 + lane * NC);
#pragma unroll
      for (int k = 0; k < 16; k++) wreg[k] = Wr[k];
    }
    __syncthreads();

    for (int j = grp; j < 64; j += 4)
      out_feats[((size_t)(b * NN + n0 + j) * NC) + lane] = tile[lane][j];

    const int d = lane;
    float acc[16];
    const float bd = b1[d];
#pragma unroll
    for (int jj = 0; jj < 16; jj++) acc[jj] = bd;

    const float4* tv = (const float4*)&tile[0][0];
#pragma unroll
    for (int k = 0; k < 16; k++) {
#pragma unroll
      for (int cc = 0; cc < 4; cc++) {
        const int c = k * 4 + cc;
        const float w = (cc == 0)   ? wreg[k].x
                        : (cc == 1) ? wreg[k].y
                        : (cc == 2) ? wreg[k].z
                                    : wreg[k].w;
#pragma unroll
        for (int q = 0; q < 4; q++) {
          const float4 v = tv[c * 17 + grp * 4 + q];
          acc[q * 4 + 0] = fmaf(v.x, w, acc[q * 4 + 0]);
          acc[q * 4 + 1] = fmaf(v.y, w, acc[q * 4 + 1]);
          acc[q * 4 + 2] = fmaf(v.z, w, acc[q * 4 + 2]);
          acc[q * 4 + 3] = fmaf(v.w, w, acc[q * 4 + 3]);
        }
      }
    }
#pragma unroll
    for (int jj = 0; jj < 16; jj++) {
      const int j = grp * 16 + jj;
      out_x[((size_t)(b * NN + n0 + j) * ND) + d] = acc[jj];
    }
    return;
  }

  // ======================= kNN path (verbatim r2) =======================
  float* px = reinterpret_cast<float*>(smem);
  float* py = px + PARTS * CHUNK;
  float* pz = py + PARTS * CHUNK;
  unsigned short* cand =
      reinterpret_cast<unsigned short*>(smem + 3 * PARTS * CHUNK * 4);
  int* ccnt =
      reinterpret_cast<int*>(smem + 3 * PARTS * CHUNK * 4 + QPB * CAP * 2);

  const int ql = t >> 3;   // query-local 0..31
  const int part = t & 7;  // 0..7

  if (t < QPB) ccnt[t] = 0;

  // stage points SoA, chunked per part with +4 float pad
  const float* P = xyz + (size_t)b * NN * 3;
  for (int i = t; i < NN; i += 256) {
    const int slot = (i >> 8) * CHUNK + (i & 255);
    px[slot] = P[3 * i + 0];
    py[slot] = P[3 * i + 1];
    pz[slot] = P[3 * i + 2];
  }
  __syncthreads();

  const int q = blockIdx.x * QPB + ql;
  const float* Q = xyz_fp + ((size_t)b * NM + q) * 3;
  const float qx = Q[0], qy = Q[1], qz = Q[2];

  const int pbase = part * CHUNK;

  // ---- pass 1: group mins (8 groups of 32 points per lane) ----
  float gmin[NG];
#pragma unroll
  for (int g = 0; g < NG; g++) {
    float gm = 3.0e38f;
#pragma unroll
    for (int bb = 0; bb < 4; bb++) {
      float d[8];
      dist8(px, py, pz, pbase + g * 32 + bb * 8, qx, qy, qz, d);
      gm = fminf(gm, min8(d));
    }
    gmin[g] = gm;
  }

  // ---- T = 16th-smallest of the query's 64 group-mins ----
  float s[16];
  {
    float g8[NG];
#pragma unroll
    for (int g = 0; g < NG; g++) g8[g] = gmin[g];
    SORT8(g8)
#pragma unroll
    for (int j = 0; j < 8; j++) s[j] = g8[j];
#pragma unroll
    for (int j = 8; j < 16; j++) s[j] = 3.0e38f;
  }
#pragma unroll
  for (int mask = 1; mask <= 4; mask <<= 1) {
    float B[16];
#pragma unroll
    for (int j = 0; j < 16; j++) B[j] = __shfl_xor(s[j], mask, 64);
    float L[16];
#pragma unroll
    for (int j = 0; j < 16; j++) L[j] = fminf(s[j], B[15 - j]);
    BITONIC16(L)
#pragma unroll
    for (int j = 0; j < 16; j++) s[j] = L[j];
  }
  const float T = s[15];

  // ---- per-lane 8-bit pass mask ----
  unsigned m8 = 0;
#pragma unroll
  for (int g = 0; g < NG; g++) m8 |= (gmin[g] <= T) ? (1u << g) : 0u;

  // ---- butterfly-OR across the query's 8 lanes -> 64-bit group mask ----
  unsigned lo = (part < 4) ? (m8 << (8 * part)) : 0u;
  unsigned hi = (part >= 4) ? (m8 << (8 * (part - 4))) : 0u;
#pragma unroll
  for (int mk = 1; mk <= 4; mk <<= 1) {
    lo |= __shfl_xor(lo, mk, 64);
    hi |= __shfl_xor(hi, mk, 64);
  }
  const unsigned long long vm = ((unsigned long long)hi << 32) | lo;

  // ---- round-robin: k-th set bit -> lane (k & 7) ----
  unsigned long long mym = 0ull;
  {
    unsigned long long m = vm;
    int cnt = 0;
    while (m) {
      const unsigned long long lb = m & (0ull - m);
      if ((cnt & 7) == part) mym |= lb;
      m ^= lb;
      cnt++;
    }
  }

  // ---- pass 2: scan assigned groups (any chunk), collect candidates ----
  while (mym) {
    const int gid = __ffsll(mym) - 1;
    mym &= mym - 1;
    const int gb = (gid >> 3) * CHUNK + (gid & 7) * 32;
    const int ib = (gid >> 3) * PPT + (gid & 7) * 32;
#pragma unroll
    for (int bb = 0; bb < 4; bb++) {
      float d[8];
      dist8(px, py, pz, gb + bb * 8, qx, qy, qz, d);
      if (min8(d) <= T) {
#pragma unroll
        for (int j = 0; j < 8; j++) {
          if (d[j] <= T) {
            const int pos = atomicAdd(&ccnt[ql], 1);
            if (pos < CAP)
              cand[ql * CAP + pos] = (unsigned short)(ib + bb * 8 + j);
          }
        }
      }
    }
  }
  __syncthreads();

  // ---- phase 3: exact stable top-16 by (d2, idx) u64 keys ----
  if (part == 0) {
    const int cnt = ccnt[ql];
    unsigned long long kb[NK];
#pragma unroll
    for (int j = 0; j < NK; j++) kb[j] = ~0ULL;

    if (cnt <= CAP) {
      for (int c = 0; c < cnt; c++) {
        const int i = cand[ql * CAP + c];
        const int slot = (i >> 8) * CHUNK + (i & 255);
        const float d2 = d2rn(qx, qy, qz, px[slot], py[slot], pz[slot]);
        unsigned long long kk =
            ((unsigned long long)__float_as_uint(d2) << 32) | (unsigned)i;
        if (kk < kb[NK - 1]) {
#pragma unroll
          for (int j = 0; j < NK; j++) {
            const bool c2 = kk < kb[j];
            const unsigned long long lo2 = c2 ? kk : kb[j];
            const unsigned long long hi2 = c2 ? kb[j] : kk;
            kb[j] = lo2;
            kk = hi2;
          }
        }
      }
    } else {
      // overflow fallback (astronomically rare): exact scan of all points
      for (int i = 0; i < NN; i++) {
        const int slot = (i >> 8) * CHUNK + (i & 255);
        const float d2 = d2rn(qx, qy, qz, px[slot], py[slot], pz[slot]);
        unsigned long long kk =
            ((unsigned long long)__float_as_uint(d2) << 32) | (unsigned)i;
        if (kk < kb[NK - 1]) {
#pragma unroll
          for (int j = 0; j < NK; j++) {
            const bool c2 = kk < kb[j];
            const unsigned long long lo2 = c2 ? kk : kb[j];
            const unsigned long long hi2 = c2 ? kb[j] : kk;
            kb[j] = lo2;
            kk = hi2;
          }
        }
      }
    }
#pragma unroll
    for (int j = 0; j < NK; j++)
      cand[ql * CAP + j] = (unsigned short)(unsigned)kb[j];
  }
  __syncthreads();

  // ---- output: each part lane writes 2 neighbors (6 floats) ----
  float* o = out_knn + ((size_t)(b * NM + q)) * (NK * 3);
#pragma unroll
  for (int jj = 0; jj < 2; jj++) {
    const int j = part * 2 + jj;
    const int i = cand[ql * CAP + j];
    const int slot = (i >> 8) * CHUNK + (i & 255);
    o[3 * j + 0] = px[slot];
    o[3 * j + 1] = py[slot];
    o[3 * j + 2] = pz[slot];
  }
}

// ---------------------------------------------------------------------------
extern "C" void kernel_launch(void* const* d_in, const int* in_sizes, int n_in,
                              void* d_out, int out_size, void* d_ws,
                              size_t ws_size, hipStream_t stream) {
  const float* xyz      = (const float*)d_in[0];  // [8,2048,3]
  const float* xyz_fp   = (const float*)d_in[1];  // [8,8192,3]
  const float* features = (const float*)d_in[2];  // [8,64,2048]
  const float* W1 = (const float*)d_in[4];        // [64,64]
  const float* b1 = (const float*)d_in[5];        // [64]

  float* out_feats = (float*)d_out;                       // 8*2048*64
  float* out_knn   = out_feats + (size_t)NB * NN * NC;    // 8*8192*16*3
  float* out_x     = out_knn + (size_t)NB * NM * NK * 3;  // 8*2048*64

  fused_kernel<<<dim3(KB + FB, NB), 256, 0, stream>>>(
      features, W1, b1, out_feats, out_x, xyz, xyz_fp, out_knn);
}